// Round 2
// baseline (330.112 us; speedup 1.0000x reference)
//
#include <hip/hip_runtime.h>
#include <hip/hip_bf16.h>

#define NB     32768
#define DDIM   256
#define KNBR   16
#define ADIM   64
#define TWOD   512
#define ROWS_PB 16
#define NTHREADS 256

using bf16x8  = __attribute__((ext_vector_type(8))) short;
using short4v = __attribute__((ext_vector_type(4))) short;
using f32x4   = __attribute__((ext_vector_type(4))) float;

__device__ __forceinline__ short f2bf(float x) {
  unsigned int u;
  __builtin_memcpy(&u, &x, 4);
  u += 0x7FFFu + ((u >> 16) & 1u);   // RNE, inputs are never NaN
  return (short)(u >> 16);
}
__device__ __forceinline__ float bf2f(short s) {
  unsigned int u = ((unsigned int)(unsigned short)s) << 16;
  float f;
  __builtin_memcpy(&f, &u, 4);
  return f;
}

// Fallback B-fragment loader, direct from f32 row-major weight (mirror k-map g*8+i)
__device__ __forceinline__ bf16x8 ldWfrag(const float* __restrict__ W, int ld, int r, int c) {
  const float4* p = (const float4*)(W + (size_t)r * ld + c);
  float4 a = p[0];
  float4 b = p[1];
  bf16x8 o;
  o[0] = f2bf(a.x); o[1] = f2bf(a.y); o[2] = f2bf(a.z); o[3] = f2bf(a.w);
  o[4] = f2bf(b.x); o[5] = f2bf(b.y); o[6] = f2bf(b.z); o[7] = f2bf(b.w);
  return o;
}

// ---- prep: convert Wq/Wk/Wg f32 -> bf16 MFMA B-fragment arrays in ws ----
// layout (shorts): [0,16384) WqF (32 frags), [16384,32768) WkF (32), [32768,163840) WgF (256)
// frag f, lane: element i = W[rowTile*16 + (lane&15)][s*32 + (lane>>4)*8 + i]
__global__ void prep_frags(const float* __restrict__ Wq,
                           const float* __restrict__ Wk,
                           const float* __restrict__ Wg,
                           short* __restrict__ F) {
  const int gid  = blockIdx.x * NTHREADS + threadIdx.x;
  const int lane = gid & 63;
  const int n16  = lane & 15;
  const int g4   = lane >> 4;
  const int f    = gid >> 6;                 // 0..319
  const float* src;
  short* dst;
  if (f < 32) {
    const int t = f >> 3, s = f & 7;
    src = Wq + (size_t)(t * 16 + n16) * DDIM + s * 32 + g4 * 8;
    dst = F + f * 512 + lane * 8;
  } else if (f < 64) {
    const int fq = f - 32;
    const int t = fq >> 3, s = fq & 7;
    src = Wk + (size_t)(t * 16 + n16) * DDIM + s * 32 + g4 * 8;
    dst = F + 16384 + fq * 512 + lane * 8;
  } else {
    const int fg = f - 64;                   // 0..255
    const int t4 = fg >> 4, s = fg & 15;
    src = Wg + (size_t)(t4 * 16 + n16) * TWOD + s * 32 + g4 * 8;
    dst = F + 32768 + fg * 512 + lane * 8;
  }
  float4 a = *(const float4*)src;
  float4 b = *(const float4*)(src + 4);
  bf16x8 o;
  o[0] = f2bf(a.x); o[1] = f2bf(a.y); o[2] = f2bf(a.z); o[3] = f2bf(a.w);
  o[4] = f2bf(b.x); o[5] = f2bf(b.y); o[6] = f2bf(b.z); o[7] = f2bf(b.w);
  *(bf16x8*)dst = o;
}

// LDS layout (shorts):
//   [0,16384)      sNbr  : per-wave neighbor tile [wave][j=16][d=256], XOR-swizzled
//   [16384,24576)  sGate : [row=16][512] bf16 (center | context), XOR-swizzled
template<bool FRAG>
__global__ __launch_bounds__(NTHREADS, 3)
void natt_fused(const float* __restrict__ center,
                const float* __restrict__ neigh,
                const float* __restrict__ nwts,
                const void*  __restrict__ vmask,
                const short* __restrict__ WF,
                const float* __restrict__ Wq, const float* __restrict__ bq,
                const float* __restrict__ Wk, const float* __restrict__ bk,
                const float* __restrict__ Wg, const float* __restrict__ bg,
                float* __restrict__ out)
{
  __shared__ __align__(16) short smem[24576];
  const int tid  = threadIdx.x;
  const int lane = tid & 63;
  const int w    = tid >> 6;
  const int n16  = lane & 15;
  const int g4   = lane >> 4;
  const int row0 = blockIdx.x * ROWS_PB;
  const unsigned char* mb = (const unsigned char*)vmask;
  const short* WqF = WF;
  const short* WkF = WF + 16384;
  const short* WgF = WF + 32768;

  // ---- valid_mask dtype detection (1-byte bool vs 4-byte int/float), wave-uniform.
  const unsigned char x1 = mb[lane * 4 + 1];
  const unsigned char x2 = mb[lane * 4 + 2];
  const unsigned char x3 = mb[lane * 4 + 3];
  const bool anyGe2 = __ballot((x1 >= 2) || (x2 >= 2) || (x3 >= 2)) != 0ULL;
  const bool anyNz  = __ballot(((x1 | x2) | x3) != 0) != 0ULL;
  const bool maskIsByte = anyNz && !anyGe2;

  // ---- stage center tile -> sGate[:,0:256] (bf16, swizzled) ----
  #pragma unroll
  for (int it = 0; it < 4; ++it) {
    const int row = it * 4 + w;
    const int d   = lane * 4;
    float4 v = *(const float4*)(center + (size_t)(row0 + row) * DDIM + d);
    short4v o;
    o[0] = f2bf(v.x); o[1] = f2bf(v.y); o[2] = f2bf(v.z); o[3] = f2bf(v.w);
    *(short4v*)&smem[16384 + ((row * 512 + d) ^ ((row & 7) << 3))] = o;
  }
  __syncthreads();

  // ---- q-projection (each wave redundantly computes q[16][64]) ----
  f32x4 qacc[4];
  #pragma unroll
  for (int t = 0; t < 4; ++t) {
    qacc[t][0] = 0.f; qacc[t][1] = 0.f; qacc[t][2] = 0.f; qacc[t][3] = 0.f;
  }
  #pragma unroll
  for (int s = 0; s < 8; ++s) {
    bf16x8 af = *(const bf16x8*)&smem[16384 + ((n16 * 512 + s * 32 + g4 * 8) ^ ((n16 & 7) << 3))];
    #pragma unroll
    for (int t = 0; t < 4; ++t) {
      bf16x8 bfr = FRAG ? *(const bf16x8*)&WqF[(t * 8 + s) * 512 + lane * 8]
                        : ldWfrag(Wq, DDIM, t * 16 + n16, s * 32 + g4 * 8);
      qacc[t] = __builtin_amdgcn_mfma_f32_16x16x32_bf16(af, bfr, qacc[t], 0, 0, 0);
    }
  }
  float qreg[4][4];
  #pragma unroll
  for (int t = 0; t < 4; ++t) {
    const float bqa = bq[t * 16 + n16];
    #pragma unroll
    for (int r = 0; r < 4; ++r) qreg[t][r] = qacc[t][r] + bqa;
  }

  // ---- per-wave rows, software-pipelined neighbor loads ----
  float4 nf[16];
  {
    const float4* np = (const float4*)(neigh + (size_t)(row0 + w * 4) * (KNBR * DDIM));
    #pragma unroll
    for (int j = 0; j < 16; ++j) nf[j] = np[j * 64 + lane];
  }

  #pragma unroll
  for (int rr = 0; rr < 4; ++rr) {
    const int rowl = w * 4 + rr;
    const size_t gr = (size_t)(row0 + rowl);

    // convert current row's prefetched regs -> LDS (bf16, swizzled)
    #pragma unroll
    for (int j = 0; j < 16; ++j) {
      short4v o;
      o[0] = f2bf(nf[j].x); o[1] = f2bf(nf[j].y); o[2] = f2bf(nf[j].z); o[3] = f2bf(nf[j].w);
      *(short4v*)&smem[w * 4096 + ((j * 256 + lane * 4) ^ ((j & 7) << 3))] = o;
    }

    // issue next row's loads (latency hides under this row's compute)
    float4 nn[16];
    if (rr < 3) {
      const float4* np = (const float4*)(neigh + (size_t)(gr + 1) * (KNBR * DDIM));
      #pragma unroll
      for (int j = 0; j < 16; ++j) nn[j] = np[j * 64 + lane];
    }

    // confidence weights (current row)
    float4 wv4[4];
    #pragma unroll
    for (int q4 = 0; q4 < 4; ++q4) wv4[q4] = *(const float4*)(nwts + gr * KNBR + q4 * 4);

    // k-projection: M=16 neighbors, N=64, K=256
    f32x4 kacc[4];
    #pragma unroll
    for (int t = 0; t < 4; ++t) {
      kacc[t][0] = 0.f; kacc[t][1] = 0.f; kacc[t][2] = 0.f; kacc[t][3] = 0.f;
    }
    #pragma unroll
    for (int s = 0; s < 8; ++s) {
      bf16x8 af = *(const bf16x8*)&smem[w * 4096 +
                    ((n16 * 256 + s * 32 + g4 * 8) ^ ((n16 & 7) << 3))];
      #pragma unroll
      for (int t = 0; t < 4; ++t) {
        bf16x8 bfr = FRAG ? *(const bf16x8*)&WkF[(t * 8 + s) * 512 + lane * 8]
                          : ldWfrag(Wk, DDIM, t * 16 + n16, s * 32 + g4 * 8);
        kacc[t] = __builtin_amdgcn_mfma_f32_16x16x32_bf16(af, bfr, kacc[t], 0, 0, 0);
      }
    }
    #pragma unroll
    for (int t = 0; t < 4; ++t) {
      const float bka = bk[t * 16 + n16];
      #pragma unroll
      for (int r = 0; r < 4; ++r) kacc[t][r] += bka;
    }

    // logits: lane holds k[j=g4*4+r][a=16t+n16]; q broadcast via shfl, reduce over a
    float part[4] = {0.f, 0.f, 0.f, 0.f};
    #pragma unroll
    for (int t = 0; t < 4; ++t) {
      const float qv = __shfl(qreg[t][rr], w * 16 + n16);
      #pragma unroll
      for (int r = 0; r < 4; ++r) part[r] += qv * kacc[t][r];
    }
    #pragma unroll
    for (int off = 1; off < 16; off <<= 1) {
      #pragma unroll
      for (int r = 0; r < 4; ++r) part[r] += __shfl_xor(part[r], off);
    }
    float att[16];
    float mx = -1e30f;
    #pragma unroll
    for (int j = 0; j < 16; ++j) {
      att[j] = 0.125f * __shfl(part[j & 3], (j >> 2) << 4);   // SCALE = 64^-0.5
      mx = fmaxf(mx, att[j]);
    }
    float sum = 0.f;
    #pragma unroll
    for (int j = 0; j < 16; ++j) { att[j] = __expf(att[j] - mx); sum += att[j]; }
    const float rs = 1.f / sum;
    float den = 1e-8f;
    #pragma unroll
    for (int j = 0; j < 16; ++j) { att[j] = att[j] * rs * wv4[j >> 2][j & 3]; den += att[j]; }
    const float rd = 1.f / den;

    // context: lane owns dims lane*4..+3
    float cx[4] = {0.f, 0.f, 0.f, 0.f};
    #pragma unroll
    for (int j = 0; j < 16; ++j) {
      short4v nv = *(const short4v*)&smem[w * 4096 +
                     ((j * 256 + lane * 4) ^ ((j & 7) << 3))];
      const float aj = att[j];
      cx[0] += aj * bf2f(nv[0]);
      cx[1] += aj * bf2f(nv[1]);
      cx[2] += aj * bf2f(nv[2]);
      cx[3] += aj * bf2f(nv[3]);
    }
    short4v co;
    co[0] = f2bf(cx[0] * rd); co[1] = f2bf(cx[1] * rd);
    co[2] = f2bf(cx[2] * rd); co[3] = f2bf(cx[3] * rd);
    *(short4v*)&smem[16384 + ((rowl * 512 + 256 + lane * 4) ^ ((rowl & 7) << 3))] = co;

    if (rr < 3) {
      #pragma unroll
      for (int j = 0; j < 16; ++j) nf[j] = nn[j];
    }
  }
  __syncthreads();

  // ---- gate GEMM (M=16 rows, N=256, K=512) + fused epilogue ----
  #pragma unroll
  for (int tt = 0; tt < 4; ++tt) {
    const int dout = (w * 4 + tt) * 16 + n16;
    f32x4 gacc;
    gacc[0] = 0.f; gacc[1] = 0.f; gacc[2] = 0.f; gacc[3] = 0.f;
    #pragma unroll
    for (int s = 0; s < 16; ++s) {
      bf16x8 af = *(const bf16x8*)&smem[16384 +
                    ((n16 * 512 + s * 32 + g4 * 8) ^ ((n16 & 7) << 3))];
      bf16x8 bfr = FRAG ? *(const bf16x8*)&WgF[((w * 4 + tt) * 16 + s) * 512 + lane * 8]
                        : ldWfrag(Wg, TWOD, dout, s * 32 + g4 * 8);
      gacc = __builtin_amdgcn_mfma_f32_16x16x32_bf16(af, bfr, gacc, 0, 0, 0);
    }
    const float bga = bg[dout];
    #pragma unroll
    for (int r = 0; r < 4; ++r) {
      const int rowl = g4 * 4 + r;
      const size_t gr = (size_t)(row0 + rowl);
      const float pre  = gacc[r] + bga;
      const float gate = 1.f / (1.f + __expf(-pre));
      const float cen  = center[gr * DDIM + dout];
      const float cxv  = bf2f(smem[16384 + ((rowl * 512 + 256 + dout) ^ ((rowl & 7) << 3))]);
      const float fused = gate * cen + (1.f - gate) * cxv;
      const bool valid = maskIsByte ? (mb[gr] != 0)
                                    : (((const unsigned int*)vmask)[gr] != 0u);
      out[gr * DDIM + dout] = valid ? fused : cen;
    }
  }
}

extern "C" void kernel_launch(void* const* d_in, const int* in_sizes, int n_in,
                              void* d_out, int out_size, void* d_ws, size_t ws_size,
                              hipStream_t stream) {
  const float* center = (const float*)d_in[0];
  const float* neigh  = (const float*)d_in[1];
  const float* nwts   = (const float*)d_in[2];
  const void*  vm     = d_in[3];
  const float* Wq = (const float*)d_in[4];
  const float* bq = (const float*)d_in[5];
  const float* Wk = (const float*)d_in[6];
  const float* bk = (const float*)d_in[7];
  const float* Wg = (const float*)d_in[8];
  const float* bg = (const float*)d_in[9];
  float* out = (float*)d_out;
  short* WF = (short*)d_ws;

  const int nrows = in_sizes[0] / DDIM;           // 32768
  dim3 grid(nrows / ROWS_PB), block(NTHREADS);

  const bool frag = ws_size >= (size_t)163840 * sizeof(short);
  if (frag) {
    hipLaunchKernelGGL(prep_frags, dim3(80), dim3(NTHREADS), 0, stream, Wq, Wk, Wg, WF);
    hipLaunchKernelGGL((natt_fused<true>), grid, block, 0, stream,
                       center, neigh, nwts, vm, WF, Wq, bq, Wk, bk, Wg, bg, out);
  } else {
    hipLaunchKernelGGL((natt_fused<false>), grid, block, 0, stream,
                       center, neigh, nwts, vm, WF, Wq, bq, Wk, bk, Wg, bg, out);
  }
}

// Round 3
// 309.385 us; speedup vs baseline: 1.0670x; 1.0670x over previous
//
#include <hip/hip_runtime.h>
#include <hip/hip_bf16.h>

#define DDIM   256
#define KNBR   16
#define TWOD   512
#define ROWS_PB 16
#define NTHREADS 256

using bf16x8  = __attribute__((ext_vector_type(8))) short;
using short4v = __attribute__((ext_vector_type(4))) short;
using f32x4   = __attribute__((ext_vector_type(4))) float;

__device__ __forceinline__ short f2bf(float x) {
  unsigned int u;
  __builtin_memcpy(&u, &x, 4);
  u += 0x7FFFu + ((u >> 16) & 1u);   // RNE, inputs are never NaN
  return (short)(u >> 16);
}
__device__ __forceinline__ float bf2f(short s) {
  unsigned int u = ((unsigned int)(unsigned short)s) << 16;
  float f;
  __builtin_memcpy(&f, &u, 4);
  return f;
}

// Fallback B-fragment loader, direct from f32 row-major weight (mirror k-map g*8+i)
__device__ __forceinline__ bf16x8 ldWfrag(const float* __restrict__ W, int ld, int r, int c) {
  const float4* p = (const float4*)(W + (size_t)r * ld + c);
  float4 a = p[0];
  float4 b = p[1];
  bf16x8 o;
  o[0] = f2bf(a.x); o[1] = f2bf(a.y); o[2] = f2bf(a.z); o[3] = f2bf(a.w);
  o[4] = f2bf(b.x); o[5] = f2bf(b.y); o[6] = f2bf(b.z); o[7] = f2bf(b.w);
  return o;
}

// ---- prep: convert Wq/Wk/Wg f32 -> bf16 MFMA B-fragment arrays in ws ----
// layout (shorts): [0,16384) WqF (32 frags), [16384,32768) WkF (32), [32768,163840) WgF (256)
__global__ void prep_frags(const float* __restrict__ Wq,
                           const float* __restrict__ Wk,
                           const float* __restrict__ Wg,
                           short* __restrict__ F) {
  const int gid  = blockIdx.x * NTHREADS + threadIdx.x;
  const int lane = gid & 63;
  const int n16  = lane & 15;
  const int g4   = lane >> 4;
  const int f    = gid >> 6;                 // 0..319
  const float* src;
  short* dst;
  if (f < 32) {
    const int t = f >> 3, s = f & 7;
    src = Wq + (size_t)(t * 16 + n16) * DDIM + s * 32 + g4 * 8;
    dst = F + f * 512 + lane * 8;
  } else if (f < 64) {
    const int fq = f - 32;
    const int t = fq >> 3, s = fq & 7;
    src = Wk + (size_t)(t * 16 + n16) * DDIM + s * 32 + g4 * 8;
    dst = F + 16384 + fq * 512 + lane * 8;
  } else {
    const int fg = f - 64;                   // 0..255
    const int t4 = fg >> 4, s = fg & 15;
    src = Wg + (size_t)(t4 * 16 + n16) * TWOD + s * 32 + g4 * 8;
    dst = F + 32768 + fg * 512 + lane * 8;
  }
  float4 a = *(const float4*)src;
  float4 b = *(const float4*)(src + 4);
  bf16x8 o;
  o[0] = f2bf(a.x); o[1] = f2bf(a.y); o[2] = f2bf(a.z); o[3] = f2bf(a.w);
  o[4] = f2bf(b.x); o[5] = f2bf(b.y); o[6] = f2bf(b.z); o[7] = f2bf(b.w);
  *(bf16x8*)dst = o;
}

// LDS (shorts): sNbr[16384] = 4 waves x [16][256] bf16 (XOR-swizzled)
//               sCtx[4096]  = [16][256] bf16, holds center (q-proj) then context
template<bool FRAG>
__global__ __launch_bounds__(NTHREADS, 4)
void natt_fused(const float* __restrict__ center,
                const float* __restrict__ neigh,
                const float* __restrict__ nwts,
                const void*  __restrict__ vmask,
                const short* __restrict__ WF,
                const float* __restrict__ Wq, const float* __restrict__ bq,
                const float* __restrict__ Wk, const float* __restrict__ bk,
                const float* __restrict__ Wg, const float* __restrict__ bg,
                float* __restrict__ out)
{
  __shared__ __align__(16) short sNbr[16384];
  __shared__ __align__(16) short sCtx[4096];
  const int tid  = threadIdx.x;
  const int lane = tid & 63;
  const int w    = tid >> 6;
  const int n16  = lane & 15;
  const int g4   = lane >> 4;
  const int row0 = blockIdx.x * ROWS_PB;
  const unsigned char* mb = (const unsigned char*)vmask;
  const short* WqF = WF;
  const short* WkF = WF + 16384;
  const short* WgF = WF + 32768;

  // ---- valid_mask dtype detection (1-byte bool vs 4-byte), wave-uniform ----
  const unsigned char x1 = mb[lane * 4 + 1];
  const unsigned char x2 = mb[lane * 4 + 2];
  const unsigned char x3 = mb[lane * 4 + 3];
  const bool anyGe2 = __ballot((x1 >= 2) || (x2 >= 2) || (x3 >= 2)) != 0ULL;
  const bool anyNz  = __ballot(((x1 | x2) | x3) != 0) != 0ULL;
  const bool maskIsByte = anyNz && !anyGe2;

  // ---- stage center tile -> sCtx bf16 (coalesced, swizzled) ----
  #pragma unroll
  for (int it = 0; it < 4; ++it) {
    const int row = it * 4 + w;
    const int d   = lane * 4;
    float4 v = *(const float4*)(center + (size_t)(row0 + row) * DDIM + d);
    short4v o;
    o[0] = f2bf(v.x); o[1] = f2bf(v.y); o[2] = f2bf(v.z); o[3] = f2bf(v.w);
    *(short4v*)&sCtx[(row * 256 + d) ^ ((row & 7) << 3)] = o;
  }
  __syncthreads();

  // ---- q-projection (each wave computes q[16][64] redundantly) ----
  f32x4 qacc[4];
  #pragma unroll
  for (int t = 0; t < 4; ++t) { qacc[t][0]=0.f; qacc[t][1]=0.f; qacc[t][2]=0.f; qacc[t][3]=0.f; }
  #pragma unroll
  for (int s = 0; s < 8; ++s) {
    bf16x8 af = *(const bf16x8*)&sCtx[(n16 * 256 + s * 32 + g4 * 8) ^ ((n16 & 7) << 3)];
    #pragma unroll
    for (int t = 0; t < 4; ++t) {
      bf16x8 bfr = FRAG ? *(const bf16x8*)&WqF[(t * 8 + s) * 512 + lane * 8]
                        : ldWfrag(Wq, DDIM, t * 16 + n16, s * 32 + g4 * 8);
      qacc[t] = __builtin_amdgcn_mfma_f32_16x16x32_bf16(af, bfr, qacc[t], 0, 0, 0);
    }
  }
  // bias + pre-shuffle this wave's 4 rows: qb[t][r] = q[w*4+r][16t+n16]
  f32x4 qb[4];
  #pragma unroll
  for (int t = 0; t < 4; ++t) {
    const float bqa = bq[t * 16 + n16];
    #pragma unroll
    for (int r = 0; r < 4; ++r) qb[t][r] = __shfl(qacc[t][r] + bqa, w * 16 + n16);
  }
  // bk bias, hoisted
  f32x4 bkv;
  #pragma unroll
  for (int t = 0; t < 4; ++t) bkv[t] = bk[t * 16 + n16];
  __syncthreads();   // all q-proj reads of sCtx done before context overwrites

  // ---- per-wave rows ----
  #pragma unroll
  for (int rr = 0; rr < 4; ++rr) {
    const int rowl = w * 4 + rr;
    const size_t gr = (size_t)(row0 + rowl);
    const float4* np = (const float4*)(neigh + gr * (size_t)(KNBR * DDIM));

    // stage neighbors in two batches of 8 (<=32 transient VGPRs)
    {
      float4 vb[8];
      #pragma unroll
      for (int j = 0; j < 8; ++j) vb[j] = np[j * 64 + lane];
      #pragma unroll
      for (int j = 0; j < 8; ++j) {
        short4v o;
        o[0]=f2bf(vb[j].x); o[1]=f2bf(vb[j].y); o[2]=f2bf(vb[j].z); o[3]=f2bf(vb[j].w);
        *(short4v*)&sNbr[w * 4096 + ((j * 256 + lane * 4) ^ ((j & 7) << 3))] = o;
      }
      #pragma unroll
      for (int j = 0; j < 8; ++j) vb[j] = np[(j + 8) * 64 + lane];
      #pragma unroll
      for (int j = 0; j < 8; ++j) {
        short4v o;
        o[0]=f2bf(vb[j].x); o[1]=f2bf(vb[j].y); o[2]=f2bf(vb[j].z); o[3]=f2bf(vb[j].w);
        *(short4v*)&sNbr[w * 4096 + (((j + 8) * 256 + lane * 4) ^ (((j + 8) & 7) << 3))] = o;
      }
    }
    // confidence weights (wave-broadcast 64B)
    f32x4 wv[4];
    #pragma unroll
    for (int q4 = 0; q4 < 4; ++q4) {
      float4 t4 = *(const float4*)(nwts + gr * KNBR + q4 * 4);
      wv[q4][0]=t4.x; wv[q4][1]=t4.y; wv[q4][2]=t4.z; wv[q4][3]=t4.w;
    }

    // k-projection: M=16 neighbors, N=64, K=256
    f32x4 kacc[4];
    #pragma unroll
    for (int t = 0; t < 4; ++t) { kacc[t][0]=0.f; kacc[t][1]=0.f; kacc[t][2]=0.f; kacc[t][3]=0.f; }
    #pragma unroll
    for (int s = 0; s < 8; ++s) {
      bf16x8 af = *(const bf16x8*)&sNbr[w * 4096 +
                    ((n16 * 256 + s * 32 + g4 * 8) ^ ((n16 & 7) << 3))];
      #pragma unroll
      for (int t = 0; t < 4; ++t) {
        bf16x8 bfr = FRAG ? *(const bf16x8*)&WkF[(t * 8 + s) * 512 + lane * 8]
                          : ldWfrag(Wk, DDIM, t * 16 + n16, s * 32 + g4 * 8);
        kacc[t] = __builtin_amdgcn_mfma_f32_16x16x32_bf16(af, bfr, kacc[t], 0, 0, 0);
      }
    }

    // logits partials: lane holds k[j=g4*4+r][a=16t+n16] (+bias); dot with q
    f32x4 part;
    part[0]=0.f; part[1]=0.f; part[2]=0.f; part[3]=0.f;
    #pragma unroll
    for (int t = 0; t < 4; ++t) {
      const float qv = qb[t][rr];
      #pragma unroll
      for (int r = 0; r < 4; ++r) part[r] += qv * (kacc[t][r] + bkv[t]);
    }
    #pragma unroll
    for (int off = 1; off < 16; off <<= 1) {
      #pragma unroll
      for (int r = 0; r < 4; ++r) part[r] += __shfl_xor(part[r], off);
    }
    // broadcast logits to all lanes, softmax + reweight (all static indices)
    f32x4 lg[4];
    #pragma unroll
    for (int j = 0; j < 16; ++j)
      lg[j >> 2][j & 3] = 0.125f * __shfl(part[j & 3], (j >> 2) << 4);
    float mx = -1e30f;
    #pragma unroll
    for (int j = 0; j < 16; ++j) mx = fmaxf(mx, lg[j >> 2][j & 3]);
    float sum = 0.f;
    #pragma unroll
    for (int j = 0; j < 16; ++j) {
      const float e = __expf(lg[j >> 2][j & 3] - mx);
      lg[j >> 2][j & 3] = e; sum += e;
    }
    const float rs = 1.f / sum;
    float den = 1e-8f;
    #pragma unroll
    for (int j = 0; j < 16; ++j) {
      const float a = lg[j >> 2][j & 3] * rs * wv[j >> 2][j & 3];
      lg[j >> 2][j & 3] = a; den += a;
    }
    const float rd = 1.f / den;

    // context: lane owns dims lane*4..+3
    f32x4 cx;
    cx[0]=0.f; cx[1]=0.f; cx[2]=0.f; cx[3]=0.f;
    #pragma unroll
    for (int j = 0; j < 16; ++j) {
      short4v nv = *(const short4v*)&sNbr[w * 4096 +
                     ((j * 256 + lane * 4) ^ ((j & 7) << 3))];
      const float aj = lg[j >> 2][j & 3];
      cx[0] += aj * bf2f(nv[0]);
      cx[1] += aj * bf2f(nv[1]);
      cx[2] += aj * bf2f(nv[2]);
      cx[3] += aj * bf2f(nv[3]);
    }
    short4v co;
    co[0] = f2bf(cx[0] * rd); co[1] = f2bf(cx[1] * rd);
    co[2] = f2bf(cx[2] * rd); co[3] = f2bf(cx[3] * rd);
    *(short4v*)&sCtx[(rowl * 256 + lane * 4) ^ ((rowl & 7) << 3)] = co;
  }
  __syncthreads();

  // ---- gate GEMM (M=16 rows, N=256, K=512) + fused epilogue ----
  f32x4 gacc[4];
  #pragma unroll
  for (int t = 0; t < 4; ++t) { gacc[t][0]=0.f; gacc[t][1]=0.f; gacc[t][2]=0.f; gacc[t][3]=0.f; }
  #pragma unroll
  for (int s = 0; s < 16; ++s) {
    bf16x8 af;
    if (s < 8) {
      // center half from global (L2-hot: staged at block start, re-read in epilogue)
      const float* cp = center + (size_t)(row0 + n16) * DDIM + s * 32 + g4 * 8;
      float4 a = *(const float4*)cp;
      float4 b = *(const float4*)(cp + 4);
      af[0]=f2bf(a.x); af[1]=f2bf(a.y); af[2]=f2bf(a.z); af[3]=f2bf(a.w);
      af[4]=f2bf(b.x); af[5]=f2bf(b.y); af[6]=f2bf(b.z); af[7]=f2bf(b.w);
    } else {
      af = *(const bf16x8*)&sCtx[(n16 * 256 + (s - 8) * 32 + g4 * 8) ^ ((n16 & 7) << 3)];
    }
    #pragma unroll
    for (int tt = 0; tt < 4; ++tt) {
      bf16x8 bfr = FRAG ? *(const bf16x8*)&WgF[(((w * 4 + tt) * 16) + s) * 512 + lane * 8]
                        : ldWfrag(Wg, TWOD, (w * 4 + tt) * 16 + n16, s * 32 + g4 * 8);
      gacc[tt] = __builtin_amdgcn_mfma_f32_16x16x32_bf16(af, bfr, gacc[tt], 0, 0, 0);
    }
  }
  #pragma unroll
  for (int tt = 0; tt < 4; ++tt) {
    const int dout = (w * 4 + tt) * 16 + n16;
    const float bga = bg[dout];
    #pragma unroll
    for (int r = 0; r < 4; ++r) {
      const int rowl = g4 * 4 + r;
      const size_t gr = (size_t)(row0 + rowl);
      const float pre  = gacc[tt][r] + bga;
      const float gate = 1.f / (1.f + __expf(-pre));
      const float cen  = center[gr * DDIM + dout];
      const float cxv  = bf2f(sCtx[(rowl * 256 + dout) ^ ((rowl & 7) << 3)]);
      const float fused = gate * cen + (1.f - gate) * cxv;
      const bool valid = maskIsByte ? (mb[gr] != 0)
                                    : (((const unsigned int*)vmask)[gr] != 0u);
      out[gr * DDIM + dout] = valid ? fused : cen;
    }
  }
}

extern "C" void kernel_launch(void* const* d_in, const int* in_sizes, int n_in,
                              void* d_out, int out_size, void* d_ws, size_t ws_size,
                              hipStream_t stream) {
  const float* center = (const float*)d_in[0];
  const float* neigh  = (const float*)d_in[1];
  const float* nwts   = (const float*)d_in[2];
  const void*  vm     = d_in[3];
  const float* Wq = (const float*)d_in[4];
  const float* bq = (const float*)d_in[5];
  const float* Wk = (const float*)d_in[6];
  const float* bk = (const float*)d_in[7];
  const float* Wg = (const float*)d_in[8];
  const float* bg = (const float*)d_in[9];
  float* out = (float*)d_out;
  short* WF = (short*)d_ws;

  const int nrows = in_sizes[0] / DDIM;           // 32768
  dim3 grid(nrows / ROWS_PB), block(NTHREADS);

  const bool frag = ws_size >= (size_t)163840 * sizeof(short);
  if (frag) {
    hipLaunchKernelGGL(prep_frags, dim3(80), dim3(NTHREADS), 0, stream, Wq, Wk, Wg, WF);
    hipLaunchKernelGGL((natt_fused<true>), grid, block, 0, stream,
                       center, neigh, nwts, vm, WF, Wq, bq, Wk, bk, Wg, bg, out);
  } else {
    hipLaunchKernelGGL((natt_fused<false>), grid, block, 0, stream,
                       center, neigh, nwts, vm, WF, Wq, bq, Wk, bk, Wg, bg, out);
  }
}